// Round 1
// baseline (9.742 us; speedup 1.0000x reference)
//
#include <hip/hip_runtime.h>

// CenterPixelMSE: out = mean_b (pred[b,0,centers[b,0],centers[b,1]] - target[b])^2
// B=512, H=W=256. Pure gather + tiny reduction -> latency/launch bound.

#define B_SIZE 512
#define H_DIM 256
#define W_DIM 256

__global__ __launch_bounds__(B_SIZE) void center_mse_kernel(
    const float* __restrict__ pred,
    const float* __restrict__ target,
    const int* __restrict__ centers,
    float* __restrict__ out)
{
    const int b = threadIdx.x;  // 0..511, one thread per batch element

    // Gather
    const int r = centers[2 * b];
    const int c = centers[2 * b + 1];
    const float p = pred[(size_t)b * (H_DIM * W_DIM) + r * W_DIM + c];
    const float t = target[b];
    const float d = p - t;
    float v = d * d;

    // Wave-64 reduction
    #pragma unroll
    for (int off = 32; off > 0; off >>= 1) {
        v += __shfl_down(v, off, 64);
    }

    // 8 wave partials -> LDS -> final reduce by wave 0
    __shared__ float partials[B_SIZE / 64];
    const int wave = b >> 6;
    const int lane = b & 63;
    if (lane == 0) partials[wave] = v;
    __syncthreads();

    if (wave == 0) {
        float s = (lane < (B_SIZE / 64)) ? partials[lane] : 0.0f;
        #pragma unroll
        for (int off = 4; off > 0; off >>= 1) {
            s += __shfl_down(s, off, 64);
        }
        if (lane == 0) out[0] = s * (1.0f / (float)B_SIZE);
    }
}

extern "C" void kernel_launch(void* const* d_in, const int* in_sizes, int n_in,
                              void* d_out, int out_size, void* d_ws, size_t ws_size,
                              hipStream_t stream) {
    const float* pred    = (const float*)d_in[0];
    const float* target  = (const float*)d_in[1];
    const int*   centers = (const int*)d_in[2];
    float* out = (float*)d_out;

    center_mse_kernel<<<1, B_SIZE, 0, stream>>>(pred, target, centers, out);
}